// Round 1
// baseline (207.942 us; speedup 1.0000x reference)
//
#include <hip/hip_runtime.h>

// Segment-sum over sorted segment_ids (packed ray samples).
// Pass A: find per-ray start offsets (exploits sortedness; handles empty rays).
// Pass B: one 64-lane wave per ray; lanes stride samples, shuffle-reduce 3 ch.

__global__ __launch_bounds__(256) void find_starts_kernel(
    const int* __restrict__ ids, int n_samples, int n_rays,
    int* __restrict__ starts) {
  int i = blockIdx.x * blockDim.x + threadIdx.x;
  if (i >= n_samples) return;
  int b = ids[i];
  int a = (i == 0) ? -1 : ids[i - 1];
  // For every ray id in (a, b], sample i is its first sample.
  for (int r = a + 1; r <= b; ++r) starts[r] = i;
  if (i == n_samples - 1) {
    // Trailing empty rays + the sentinel end.
    for (int r = b + 1; r <= n_rays; ++r) starts[r] = n_samples;
  }
}

__global__ __launch_bounds__(256) void reduce_rays_kernel(
    const float* __restrict__ rgb, const float* __restrict__ w,
    const int* __restrict__ starts, float* __restrict__ out, int n_rays) {
  int gtid = blockIdx.x * blockDim.x + threadIdx.x;
  int ray = gtid >> 6;           // one wave (64 lanes) per ray
  int lane = threadIdx.x & 63;
  if (ray >= n_rays) return;
  int s0 = starts[ray];
  int s1 = starts[ray + 1];
  float r = 0.f, g = 0.f, b = 0.f;
  for (int s = s0 + lane; s < s1; s += 64) {
    float ww = w[s];
    r += ww * rgb[3 * s + 0];
    g += ww * rgb[3 * s + 1];
    b += ww * rgb[3 * s + 2];
  }
  // Wave-64 butterfly reduction.
  for (int off = 32; off; off >>= 1) {
    r += __shfl_down(r, off, 64);
    g += __shfl_down(g, off, 64);
    b += __shfl_down(b, off, 64);
  }
  if (lane == 0) {
    out[3 * ray + 0] = r;
    out[3 * ray + 1] = g;
    out[3 * ray + 2] = b;
  }
}

extern "C" void kernel_launch(void* const* d_in, const int* in_sizes, int n_in,
                              void* d_out, int out_size, void* d_ws, size_t ws_size,
                              hipStream_t stream) {
  const int*   segment_ids = (const int*)d_in[0];
  const float* rgb         = (const float*)d_in[1];
  const float* weights     = (const float*)d_in[2];
  float*       out         = (float*)d_out;

  const int n_samples = in_sizes[0];
  const int n_rays    = out_size / 3;   // out is [n_rays, 3]

  int* starts = (int*)d_ws;             // (n_rays + 1) ints

  {
    int threads = 256;
    int blocks = (n_samples + threads - 1) / threads;
    find_starts_kernel<<<blocks, threads, 0, stream>>>(
        segment_ids, n_samples, n_rays, starts);
  }
  {
    int threads = 256;                  // 4 waves/block, 1 wave/ray
    long long total_threads = (long long)n_rays * 64;
    int blocks = (int)((total_threads + threads - 1) / threads);
    reduce_rays_kernel<<<blocks, threads, 0, stream>>>(
        rgb, weights, starts, out, n_rays);
  }
}